// Round 5
// baseline (102391.602 us; speedup 1.0000x reference)
//
#include <hip/hip_runtime.h>
#include <cstdint>

// ---------------- problem constants ----------------
#define SEQ   512
#define BATCH 64
#define HID   512
#define BH    (BATCH*HID)          // 32768
#define NWG   8                    // workgroups per pool
#define NTHR  512                  // 8 waves

#define MOG_ELEMS   (5*512*512)                  // 1310720
#define GATE_ELEMS  (2048*512)                   // 1048576
#define LAYER_ELEMS (MOG_ELEMS + 2*GATE_ELEMS)   // 3407872

// ---------------- ws layout (bytes) ----------------
// flags padded: one u32 per 64B line
#define WS_CNT0  0          // pool0: 512*6 flags * 64B = 196608
#define WS_CNT1  196608     // pool1: 196608
#define WS_IAB   393216     // 512 * 64B
#define WS_IBA   425984     // 512 * 64B
#define WS_H16   458752     // 2 pools * [8][64][64] f16 = 131072
#define ZERO_PREFIX 589824  // flags + h16 zeroed each launch
#define WS_X16   589824     // 2 pools * [8][64][64] f16 = 131072
#define WS_RING  720896     // 4 slots * BH * 4B = 524288 (h1 f32, pool0->pool1)
#define WS_WT    1245184    // 2 layers * LAYER_ELEMS * 2B = 13631488 (end 14876672)

// d_out layout (floats)
#define OUT_H 16777216
#define OUT_C 16842752

typedef _Float16 f16x8 __attribute__((ext_vector_type(8)));
typedef float    f32x4 __attribute__((ext_vector_type(4)));

#define MFMA(a,b,c) __builtin_amdgcn_mfma_f32_16x16x32_f16((a),(b),(c),0,0,0)

// ---------------- coherent (bypass local L1/L2) access, coalesced ----------------
#define GLD16P(dst, ptr) \
    asm volatile("global_load_dwordx4 %0, %1, off sc0 sc1" : "=v"(dst) : "v"(ptr))
#define GLDF(dst, addr) \
    asm volatile("global_load_dword %0, %1, off sc0 sc1" : "=v"(dst) : "v"(addr))
#define VMWAIT() asm volatile("s_waitcnt vmcnt(0)" ::: "memory")
#define TIE(x)   asm volatile("" : "+v"(x))

__device__ __forceinline__ void st_h16(_Float16* p, _Float16 v) {
    unsigned b = (unsigned)__builtin_bit_cast(unsigned short, v);
    asm volatile("global_store_short %0, %1, off sc0 sc1" :: "v"(p), "v"(b) : "memory");
}
__device__ __forceinline__ void st_f32cc(float* p, float v) {
    asm volatile("global_store_dword %0, %1, off sc0 sc1" :: "v"(p), "v"(v) : "memory");
}

// ---------------- sync primitives (R2/R4-proven; no cache-wide ops) ----------------
#define FLAG(base, i) ((unsigned*)(base) + (size_t)(i) * 16)   // 64B stride

__device__ __forceinline__ void wg_wait(unsigned* c, unsigned tgt) {
    if (threadIdx.x == 0) {
        while (__hip_atomic_load(c, __ATOMIC_RELAXED, __HIP_MEMORY_SCOPE_AGENT) < tgt) { }
    }
    __syncthreads();
}
// __syncthreads drains every wave's vmcnt (sc0sc1 store acks = at coherence point)
// before tid0 publishes.
__device__ __forceinline__ void wg_signal(unsigned* c) {
    __syncthreads();
    if (threadIdx.x == 0)
        __hip_atomic_fetch_add(c, 1u, __ATOMIC_RELAXED, __HIP_MEMORY_SCOPE_AGENT);
}

__device__ __forceinline__ float sigf(float z) { return 1.f / (1.f + __expf(-z)); }

// Reordered gate layout: rg = 64*b + 16*gate + j  <->  orig row = gate*512 + 16*b + j
__device__ __forceinline__ int gate_orig_row(int rg) {
    return ((rg >> 4) & 3) * 512 + ((rg >> 6) << 4) + (rg & 15);
}

// ---------------- prologue: f32 -> f16 weight conversion + gate reorder --------
__global__ __launch_bounds__(256)
void prologue_convert(const float* __restrict__ l1_mogW, const float* __restrict__ l1_Wih,
                      const float* __restrict__ l1_Whh,
                      const float* __restrict__ l2_mogW, const float* __restrict__ l2_Wih,
                      const float* __restrict__ l2_Whh,  char* __restrict__ ws)
{
    _Float16* wdst = (_Float16*)(ws + WS_WT);
    const int total = 2 * LAYER_ELEMS;
    const int stride = gridDim.x * blockDim.x;
    for (int idx = blockIdx.x * blockDim.x + threadIdx.x; idx < total; idx += stride) {
        const int layer = idx >= LAYER_ELEMS;
        const int r = idx - layer * LAYER_ELEMS;
        float v;
        if (r < MOG_ELEMS) {
            v = (layer ? l2_mogW : l1_mogW)[r];
        } else {
            const int q = r - MOG_ELEMS;
            const int mat = q >= GATE_ELEMS;
            const int e = q - mat * GATE_ELEMS;
            const int rg = e >> 9;
            const int k  = e & 511;
            const int orig = gate_orig_row(rg);
            const float* W = mat ? (layer ? l2_Whh : l1_Whh)
                                 : (layer ? l2_Wih : l1_Wih);
            v = W[orig * 512 + k];
        }
        wdst[idx] = (_Float16)v;
    }
}

// ---------------- persistent kernel ----------------
// grid = 16 x 512. Pool = layer. WG w owns output cols [64w, 64w+64).
// Activations live in slice-major global buffers [8][64][64] f16 (sc0sc1 path)
// and are staged through LDS once per phase per WG (coalesced dwordx4).
// LDS swizzle: element col' = col ^ ((row&7)<<3)  (16B-slot XOR, G4).
__global__ __launch_bounds__(NTHR, 1)
void moglstm_persist(const float* __restrict__ in_seq,
                     const float* __restrict__ mogb1, const float* __restrict__ mogb2,
                     const float* __restrict__ bih1,  const float* __restrict__ bhh1,
                     const float* __restrict__ bih2,  const float* __restrict__ bhh2,
                     float* __restrict__ out, char* __restrict__ ws)
{
    const int pool = blockIdx.x >> 3;
    const int w    = blockIdx.x & 7;
    const int tid  = threadIdx.x;
    const int lane = tid & 63;
    const int wv   = tid >> 6;

    extern __shared__ _Float16 smem[];     // 131072 B
    _Float16* hlds = smem;                 // [8][64][64]
    _Float16* xlds = smem + 32768;         // [8][64][64]

    unsigned* cntP = (unsigned*)(ws + (pool ? WS_CNT1 : WS_CNT0));
    unsigned* iab  = (unsigned*)(ws + WS_IAB);
    unsigned* iba  = (unsigned*)(ws + WS_IBA);

    _Float16* h16g = (_Float16*)(ws + WS_H16) + pool * 32768;   // [8][64][64]
    _Float16* x16g = (_Float16*)(ws + WS_X16) + pool * 32768;
    float*    ring = (float*)(ws + WS_RING);
    const _Float16* Wb   = (const _Float16*)(ws + WS_WT) + (size_t)pool * LAYER_ELEMS;
    const _Float16* mogW = Wb;
    const _Float16* wihR = Wb + MOG_ELEMS;
    const _Float16* whhR = wihR + GATE_ELEMS;
    const float* mogb = pool ? mogb2 : mogb1;
    const float* bih  = pool ? bih2 : bih1;
    const float* bhh  = pool ? bhh2 : bhh1;

    const int rt  = wv & 3;
    const int b0  = wv >> 2;
    const int j   = lane & 15;
    const int hi  = lane >> 4;
    const int kof = hi * 8;
    const int arow  = 16 * rt + j;          // A-frag row (batch row)
    const int erow0 = 16 * rt + hi * 4;     // C/D row base
    const int c0 = 16 * b0 + j;             // within-slice cols
    const int c1 = c0 + 32;
    const int gcol0 = 64 * w + c0;          // global cols (bias/out/ring/in_seq)
    const int gcol1 = 64 * w + c1;

    // biases hoisted
    float mb[5][2];
    #pragma unroll
    for (int p = 0; p < 5; ++p) { mb[p][0] = mogb[p*512 + gcol0]; mb[p][1] = mogb[p*512 + gcol1]; }
    float gb[2][4];
    #pragma unroll
    for (int q = 0; q < 2; ++q) {
        const int hc = q ? gcol1 : gcol0;
        #pragma unroll
        for (int g = 0; g < 4; ++g) gb[q][g] = bih[g*512 + hc] + bhh[g*512 + hc];
    }

    // zero h staging LDS (h(t=0) = 0); global h16g zeroed by memset
    #pragma unroll
    for (int i = 0; i < 8; ++i)
        *(f16x8*)&hlds[(i * NTHR + tid) * 8] = (f16x8)(_Float16)0.f;
    __syncthreads();

    // staging map: thread covers 16B at byte offset tid*16 of a slice
    const int srow  = tid >> 3;                               // staged row
    const int sslot = ((tid & 7) ^ (srow & 7)) * 8;           // swizzled element col
    const int sdst  = srow * 64 + sslot;                      // within-slice LDS elem idx

    float xreg[2][4];
    float hreg[2][4] = {};
    float creg[2][4] = {};

    for (int t = 0; t < SEQ; ++t) {
        // ---------------- mogrifier phases 0..4 ----------------
        #pragma unroll
        for (int p = 0; p < 5; ++p) {
            const int isH = ((p & 1) == 0);          // even: A = h; odd: A = x
            _Float16* aLds = isH ? hlds : xlds;      // operand staging buffer
            _Float16* oLds = isH ? xlds : hlds;      // own-slot target (output)
            _Float16* aG   = isH ? h16g : x16g;
            _Float16* oG   = isH ? x16g : h16g;

            const _Float16* Wp  = mogW + p * (512 * 512);
            const _Float16* bp0 = Wp + (size_t)gcol0 * 512 + kof;
            const _Float16* bp1 = Wp + (size_t)gcol1 * 512 + kof;

            // preload col0 weights (cached; hides under the flag spin)
            f16x8 w0[16];
            #pragma unroll
            for (int ks = 0; ks < 16; ++ks) w0[ks] = *(const f16x8*)(bp0 + ks * 32);

            if (p == 0) {
                if (t > 0) wg_wait(FLAG(cntP, (t - 1) * 6 + 5), NWG);
                if (pool == 1) wg_wait(FLAG(iab, t), NWG);
            } else {
                wg_wait(FLAG(cntP, t * 6 + p - 1), NWG);
            }

            // ---- stage 7 foreign slices (coalesced dwordx4, one vmcnt) ----
            float rv[2][4];
            if (p == 0 && pool == 1) {
                #pragma unroll
                for (int q = 0; q < 2; ++q) {
                    const float* rp = ring + (t & 3) * BH + erow0 * 512 + (q ? gcol1 : gcol0);
                    #pragma unroll
                    for (int r = 0; r < 4; ++r) GLDF(rv[q][r], rp + r * 512);
                }
            }
            f16x8 st[7];
            #pragma unroll
            for (int i = 0; i < 7; ++i) {
                const int s = (w + 1 + i) & 7;
                const char* sp = (const char*)(aG + s * 4096) + tid * 16;
                GLD16P(st[i], sp);
            }
            VMWAIT();
            #pragma unroll
            for (int i = 0; i < 7; ++i) TIE(st[i]);
            if (p == 0 && pool == 1) {
                #pragma unroll
                for (int q = 0; q < 2; ++q) { TIE(rv[q][0]); TIE(rv[q][1]); TIE(rv[q][2]); TIE(rv[q][3]); }
            }
            #pragma unroll
            for (int i = 0; i < 7; ++i) {
                const int s = (w + 1 + i) & 7;
                *(f16x8*)&aLds[s * 4096 + sdst] = st[i];
            }
            __syncthreads();   // stage complete

            // ---- A-frags from LDS + MFMA ----
            f16x8 a[16];
            #pragma unroll
            for (int ks = 0; ks < 16; ++ks) {
                const int k = ks * 32 + kof;
                a[ks] = *(const f16x8*)&aLds[(k >> 6) * 4096 + arow * 64 + ((k & 63) ^ ((arow & 7) << 3))];
            }
            f32x4 acc0 = {0.f,0.f,0.f,0.f}, acc1 = {0.f,0.f,0.f,0.f};
            #pragma unroll
            for (int ks = 0; ks < 16; ++ks) acc0 = MFMA(a[ks], w0[ks], acc0);
            #pragma unroll
            for (int ks = 0; ks < 16; ++ks) acc1 = MFMA(a[ks], *(const f16x8*)(bp1 + ks * 32), acc1);

            // ---- epilogue: update masters, publish slice (global + own LDS slot) ----
            #pragma unroll
            for (int q = 0; q < 2; ++q) {
                const f32x4 acv = q ? acc1 : acc0;
                const int c  = q ? c1 : c0;
                const int gc = q ? gcol1 : gcol0;
                #pragma unroll
                for (int r = 0; r < 4; ++r) {
                    const int row = erow0 + r;
                    const float s = 2.f * sigf(acv[r] + mb[p][q]);
                    float nv;
                    if (isH) {      // x-update
                        float xo;
                        if (p == 0) xo = (pool == 0) ? in_seq[(size_t)t * BH + row * 512 + gc]
                                                     : rv[q][r];
                        else        xo = xreg[q][r];
                        nv = s * xo;
                        xreg[q][r] = nv;
                    } else {        // h-update
                        nv = s * hreg[q][r];
                        hreg[q][r] = nv;
                    }
                    const _Float16 nv16 = (_Float16)nv;
                    st_h16(&oG[w * 4096 + row * 64 + c], nv16);
                    oLds[w * 4096 + row * 64 + (c ^ ((row & 7) << 3))] = nv16;
                }
            }
            wg_signal(FLAG(cntP, t * 6 + p));
            if (p == 0 && pool == 1 && tid == 0)
                __hip_atomic_fetch_add(FLAG(iba, t), 1u, __ATOMIC_RELAXED, __HIP_MEMORY_SCOPE_AGENT);
        }

        // ---------------- LSTM gates ----------------
        // A-operands: x (after p4) staged now into xlds; h (after p3) already in hlds from p4.
        wg_wait(FLAG(cntP, t * 6 + 4), NWG);
        if (pool == 0 && t >= 4) wg_wait(FLAG(iba, t - 4), NWG);   // ring slot free

        {
            f16x8 st[7];
            #pragma unroll
            for (int i = 0; i < 7; ++i) {
                const int s = (w + 1 + i) & 7;
                const char* sp = (const char*)(x16g + s * 4096) + tid * 16;
                GLD16P(st[i], sp);
            }
            VMWAIT();
            #pragma unroll
            for (int i = 0; i < 7; ++i) TIE(st[i]);
            #pragma unroll
            for (int i = 0; i < 7; ++i) {
                const int s = (w + 1 + i) & 7;
                *(f16x8*)&xlds[s * 4096 + sdst] = st[i];
            }
        }
        __syncthreads();

        f16x8 ax[16], ah[16];
        #pragma unroll
        for (int ks = 0; ks < 16; ++ks) {
            const int k = ks * 32 + kof;
            const int o = (k >> 6) * 4096 + arow * 64 + ((k & 63) ^ ((arow & 7) << 3));
            ax[ks] = *(const f16x8*)&xlds[o];
            ah[ks] = *(const f16x8*)&hlds[o];
        }

        f32x4 acg[2][4] = {};
        #pragma unroll
        for (int q = 0; q < 2; ++q) {
            const size_t rg = (size_t)(256 * w + 64 * (b0 + 2 * q) + j) * 512 + kof;
            const _Float16* bi  = wihR + rg;
            const _Float16* bh_ = whhR + rg;
            #pragma unroll
            for (int ks = 0; ks < 16; ++ks) {
                const int o = ks * 32;
                acg[q][0] = MFMA(ax[ks], *(const f16x8*)(bi  +         o), acg[q][0]);
                acg[q][0] = MFMA(ah[ks], *(const f16x8*)(bh_ +         o), acg[q][0]);
                acg[q][1] = MFMA(ax[ks], *(const f16x8*)(bi  +  8192 + o), acg[q][1]);
                acg[q][1] = MFMA(ah[ks], *(const f16x8*)(bh_ +  8192 + o), acg[q][1]);
                acg[q][2] = MFMA(ax[ks], *(const f16x8*)(bi  + 16384 + o), acg[q][2]);
                acg[q][2] = MFMA(ah[ks], *(const f16x8*)(bh_ + 16384 + o), acg[q][2]);
                acg[q][3] = MFMA(ax[ks], *(const f16x8*)(bi  + 24576 + o), acg[q][3]);
                acg[q][3] = MFMA(ah[ks], *(const f16x8*)(bh_ + 24576 + o), acg[q][3]);
            }
        }

        __syncthreads();   // all hlds frag-reads done before epilogue rewrites hlds[w]

        #pragma unroll
        for (int q = 0; q < 2; ++q) {
            const int c  = q ? c1 : c0;
            const int gc = q ? gcol1 : gcol0;
            #pragma unroll
            for (int r = 0; r < 4; ++r) {
                const int row = erow0 + r;
                const float ig = sigf (acg[q][0][r] + gb[q][0]);
                const float fg = sigf (acg[q][1][r] + gb[q][1]);
                const float gg = tanhf(acg[q][2][r] + gb[q][2]);
                const float og = sigf (acg[q][3][r] + gb[q][3]);
                const float cn = fg * creg[q][r] + ig * gg;
                creg[q][r] = cn;
                const float hn = og * tanhf(cn);
                hreg[q][r] = hn;
                const _Float16 hn16 = (_Float16)hn;
                st_h16(&h16g[w * 4096 + row * 64 + c], hn16);
                hlds[w * 4096 + row * 64 + (c ^ ((row & 7) << 3))] = hn16;
                if (pool == 0) st_f32cc(&ring[(t & 3) * BH + row * 512 + gc], hn);
                else __builtin_nontemporal_store(hn, &out[(size_t)t * BH + row * 512 + gc]);
                if (t == SEQ - 1) {
                    __builtin_nontemporal_store(hn, &out[OUT_H + pool * BH + row * 512 + gc]);
                    __builtin_nontemporal_store(cn, &out[OUT_C + pool * BH + row * 512 + gc]);
                }
            }
        }
        wg_signal(FLAG(cntP, t * 6 + 5));
        if (pool == 0 && tid == 0)
            __hip_atomic_fetch_add(FLAG(iab, t), 1u, __ATOMIC_RELAXED, __HIP_MEMORY_SCOPE_AGENT);
    }
}

// ---------------- host launch ----------------
extern "C" void kernel_launch(void* const* d_in, const int* in_sizes, int n_in,
                              void* d_out, int out_size, void* d_ws, size_t ws_size,
                              hipStream_t stream) {
    const float* in_seq  = (const float*)d_in[0];
    const float* l1_mogW = (const float*)d_in[1];
    const float* l1_mogb = (const float*)d_in[2];
    const float* l1_Wih  = (const float*)d_in[3];
    const float* l1_Whh  = (const float*)d_in[4];
    const float* l1_bih  = (const float*)d_in[5];
    const float* l1_bhh  = (const float*)d_in[6];
    const float* l2_mogW = (const float*)d_in[7];
    const float* l2_mogb = (const float*)d_in[8];
    const float* l2_Wih  = (const float*)d_in[9];
    const float* l2_Whh  = (const float*)d_in[10];
    const float* l2_bih  = (const float*)d_in[11];
    const float* l2_bhh  = (const float*)d_in[12];

    hipMemsetAsync(d_ws, 0, ZERO_PREFIX, stream);

    prologue_convert<<<256, 256, 0, stream>>>(l1_mogW, l1_Wih, l1_Whh,
                                              l2_mogW, l2_Wih, l2_Whh, (char*)d_ws);

    moglstm_persist<<<16, NTHR, 131072, stream>>>(in_seq, l1_mogb, l2_mogb,
                                                  l1_bih, l1_bhh, l2_bih, l2_bhh,
                                                  (float*)d_out, (char*)d_ws);
}

// Round 6
// 34273.801 us; speedup vs baseline: 2.9875x; 2.9875x over previous
//
#include <hip/hip_runtime.h>
#include <cstdint>

// ---------------- problem constants ----------------
#define SEQ   512
#define BATCH 64
#define HID   512
#define BH    (BATCH*HID)
#define NWGP  32                   // workgroups per pool
#define NTHR  256                  // 4 waves

#define MOG_ELEMS   (5*512*512)                  // 1310720
#define GATE_ELEMS  (2048*512)                   // 1048576
#define LAYER_ELEMS (MOG_ELEMS + 2*GATE_ELEMS)   // 3407872

// ---------------- ws layout (bytes) ----------------
#define WS_CNT   0                // 2 pools * 512 t * 6 phases * 4B = 24576
#define WS_H32   24576            // 2 pools * BH * 4B = 262144
#define WS_H16   286720           // 2 pools * 2 bufs * BH * 2B = 262144
#define ZERO_PREFIX 548864        // cnt + h32 + h16 zeroed each launch
#define WS_X16   548864           // 2 pools * BH * 2B = 131072
#define WS_RING  679936           // 4 slots * BH * 4B = 524288 (h1 ring, f32)
#define WS_WT    1204224          // 2 layers * LAYER_ELEMS * 2B = 13631488

// d_out layout (floats)
#define OUT_H 16777216            // last_hidden [2,64,512]
#define OUT_C 16842752            // last_cell   [2,64,512]

typedef _Float16 f16x8 __attribute__((ext_vector_type(8)));
typedef float    f32x4 __attribute__((ext_vector_type(4)));

#define MFMA(a,b,c) __builtin_amdgcn_mfma_f32_16x16x32_f16((a),(b),(c),0,0,0)

// Reordered gate layout: rg = 64*b + 16*gate + j  <->  orig row = gate*512 + 16*b + j
__device__ __forceinline__ int gate_orig_row(int rg) {
    return ((rg >> 4) & 3) * 512 + ((rg >> 6) << 4) + (rg & 15);
}

// ---------------- prologue: f32 -> f16 weight conversion + gate reorder ----------------
__global__ __launch_bounds__(256)
void prologue_convert(const float* __restrict__ l1_mogW, const float* __restrict__ l1_Wih,
                      const float* __restrict__ l1_Whh,
                      const float* __restrict__ l2_mogW, const float* __restrict__ l2_Wih,
                      const float* __restrict__ l2_Whh,  char* __restrict__ ws)
{
    _Float16* wdst = (_Float16*)(ws + WS_WT);
    const int total = 2 * LAYER_ELEMS;
    const int stride = gridDim.x * blockDim.x;
    for (int idx = blockIdx.x * blockDim.x + threadIdx.x; idx < total; idx += stride) {
        const int layer = idx >= LAYER_ELEMS;
        const int r = idx - layer * LAYER_ELEMS;
        float v;
        if (r < MOG_ELEMS) {
            v = (layer ? l2_mogW : l1_mogW)[r];
        } else {
            const int q = r - MOG_ELEMS;
            const int mat = q >= GATE_ELEMS;          // 0 = Wih, 1 = Whh
            const int e = q - mat * GATE_ELEMS;
            const int rg = e >> 9;
            const int k  = e & 511;
            const int orig = gate_orig_row(rg);
            const float* W = mat ? (layer ? l2_Whh : l1_Whh)
                                 : (layer ? l2_Wih : l1_Wih);
            v = W[orig * 512 + k];
        }
        wdst[idx] = (_Float16)v;
    }
}

// ---------------- sync primitives ----------------
// wait: RELAXED spin (sc1 load, no cache-wide ops), then ONE acquire load
// (single buffer_inv per phase). Cached activation lines get refreshed; LDS
// (mog weights) is immune to the invalidate.
__device__ __forceinline__ void wg_wait(const unsigned* c, unsigned tgt) {
    if (threadIdx.x == 0) {
        while (__hip_atomic_load(c, __ATOMIC_RELAXED, __HIP_MEMORY_SCOPE_AGENT) < tgt)
            __builtin_amdgcn_s_sleep(1);
        (void)__hip_atomic_load(c, __ATOMIC_ACQUIRE, __HIP_MEMORY_SCOPE_AGENT);
    }
    __syncthreads();
}
// signal: __syncthreads drains all waves' stores (write-through L1 -> dirty L2),
// RELEASE fetch_add does ONE wbL2 then the IC-visible add. No invalidate here.
__device__ __forceinline__ void wg_signal(unsigned* c) {
    __syncthreads();
    if (threadIdx.x == 0)
        __hip_atomic_fetch_add(c, 1u, __ATOMIC_RELEASE, __HIP_MEMORY_SCOPE_AGENT);
}

__device__ __forceinline__ float sigf(float z) { return 1.f / (1.f + __expf(-z)); }

// ---------------- persistent kernel ----------------
// grid = 64 x 256 (R1-proven topology). Pool 0 = blocks 0..31 (layer 1), pool 1 = layer 2.
// WG w owns 16 output cols. Wave wv: rows [16wv,16wv+16). All bulk data on the
// normal cached path; cross-WG visibility via {release fetch_add | relaxed spin +
// one acquire}. Mog weights live in LDS (invalidate-proof).
__global__ __launch_bounds__(NTHR, 1)
void moglstm_persist(const float* __restrict__ in_seq,
                     const float* __restrict__ mogb1, const float* __restrict__ mogb2,
                     const float* __restrict__ bih1,  const float* __restrict__ bhh1,
                     const float* __restrict__ bih2,  const float* __restrict__ bhh2,
                     float* __restrict__ out, char* __restrict__ ws)
{
    const int pool = blockIdx.x >> 5;
    const int w    = blockIdx.x & 31;
    const int tid  = threadIdx.x;
    const int lane = tid & 63;
    const int wv   = tid >> 6;

    extern __shared__ char smem[];
    _Float16* wlds = (_Float16*)smem;              // [5][16][512] swizzled, 80 KB
    float*    glds = (float*)(smem + 81920);       // [64][64] gate redistr, 16 KB

    unsigned* cnt  = (unsigned*)(ws + WS_CNT);
    unsigned* cntA = cnt;                          // pool 0 counters
    unsigned* cntB = cnt + SEQ * 6;                // pool 1 counters
    unsigned* cntP = cnt + pool * SEQ * 6;

    float*     h32  = (float*)(ws + WS_H32) + pool * BH;
    _Float16*  h16v = (_Float16*)(ws + WS_H16) + pool * (2 * BH);
    _Float16*  x16v = (_Float16*)(ws + WS_X16) + pool * BH;
    float*     ring = (float*)(ws + WS_RING);
    const _Float16* Wb   = (const _Float16*)(ws + WS_WT) + (size_t)pool * LAYER_ELEMS;
    const _Float16* mogW = Wb;
    const _Float16* wihR = Wb + MOG_ELEMS;
    const _Float16* whhR = wihR + GATE_ELEMS;
    const float* mogb = pool ? mogb2 : mogb1;
    const float* bih  = pool ? bih2 : bih1;
    const float* bhh  = pool ? bhh2 : bhh1;

    // fragment / epilogue coordinates (R1 map)
    const int j     = lane & 15;
    const int hi    = lane >> 4;
    const int kof   = hi * 8;
    const int arow  = 16 * wv + j;        // A row (m)
    const int erow0 = 16 * wv + hi * 4;   // C/D row base
    const int ecol  = 16 * w + j;         // C/D col (global h-col)
    // gates pointwise coordinates (fixed thread<->cell ownership for c-state)
    const int prow0 = 4 * (tid >> 4);
    const int pj    = tid & 15;
    const int pcol  = 16 * w + pj;

    // ---- stage mog weights into LDS (once; immune to buffer_inv) ----
    // layout: wlds[(p*16 + c)*512 + (k ^ ((c&7)<<3))], 16B-slot XOR swizzle
    for (int i = tid; i < 5 * 16 * 64; i += NTHR) {
        const int p   = i >> 10;          // /1024
        const int rem = i & 1023;
        const int c   = rem >> 6;
        const int k   = (rem & 63) << 3;
        f16x8 v = *(const f16x8*)(mogW + ((size_t)p * 512 + 16 * w + c) * 512 + k);
        *(f16x8*)&wlds[((p * 16 + c) << 9) + (k ^ ((c & 7) << 3))] = v;
    }
    __syncthreads();

    // B-frag LDS base for this lane (col = j)
    const int cxor = (j & 7) << 3;

    // biases hoisted into registers
    float mb[5];
    #pragma unroll
    for (int p = 0; p < 5; ++p) mb[p] = mogb[p * 512 + ecol];
    float gbias[4];
    #pragma unroll
    for (int g = 0; g < 4; ++g) gbias[g] = bih[g * 512 + 16 * w + j] + bhh[g * 512 + 16 * w + j];

    float xreg[4];
    float creg[4] = {0.f, 0.f, 0.f, 0.f};

    for (int t = 0; t < SEQ; ++t) {
        _Float16* hb = h16v + (t & 1) * BH;          // h read/updated during step t
        _Float16* ho = h16v + ((t & 1) ^ 1) * BH;    // gates write next-step h here

        // ---------------- mogrifier phases 0..4 ----------------
        #pragma unroll
        for (int p = 0; p < 5; ++p) {
            if (p == 0) {
                if (t > 0) wg_wait(&cntP[(t - 1) * 6 + 5], NWGP);   // own gates(t-1)
                if (pool == 1) wg_wait(&cntA[t * 6 + 5], NWGP);     // h1[t] in ring
            } else {
                wg_wait(&cntP[t * 6 + p - 1], NWGP);
            }

            // p even: x = 2*sig(h @ W^T + b) * x ; p odd: h = 2*sig(x @ W^T + b) * h
            const _Float16* act = (p & 1) ? x16v : hb;
            const _Float16* ap  = act + arow * 512 + kof;
            const _Float16* wl  = wlds + ((p * 16 + j) << 9);

            f32x4 acc = {0.f, 0.f, 0.f, 0.f};
            #pragma unroll
            for (int ks = 0; ks < 16; ++ks) {
                f16x8 a  = *(const f16x8*)(ap + ks * 32);                    // cached global
                f16x8 bw = *(const f16x8*)&wl[(kof + ks * 32) ^ cxor];       // LDS
                acc = MFMA(a, bw, acc);
            }
            #pragma unroll
            for (int r = 0; r < 4; ++r) {
                const int row = erow0 + r;
                const float s = 2.f * sigf(acc[r] + mb[p]);
                if ((p & 1) == 0) {
                    float xo;
                    if (p == 0) {
                        xo = (pool == 0) ? in_seq[(size_t)t * BH + row * HID + ecol]
                                         : ring[(t & 3) * BH + row * HID + ecol];
                    } else {
                        xo = xreg[r];
                    }
                    const float xn = s * xo;
                    xreg[r] = xn;
                    x16v[row * HID + ecol] = (_Float16)xn;
                } else {
                    const float hn = s * h32[row * HID + ecol];
                    h32[row * HID + ecol] = hn;
                    hb[row * HID + ecol] = (_Float16)hn;
                }
            }
            wg_signal(&cntP[t * 6 + p]);
        }

        // ---------------- LSTM gates ----------------
        wg_wait(&cntP[t * 6 + 4], NWGP);
        if (pool == 0 && t >= 4) wg_wait(&cntB[(t - 4) * 6 + 0], NWGP);  // ring slot free

        f32x4 g0 = {0,0,0,0}, g1 = {0,0,0,0}, g2 = {0,0,0,0}, g3 = {0,0,0,0};
        {
            const _Float16* xa = x16v + arow * 512 + kof;
            const _Float16* ha = hb   + arow * 512 + kof;
            const int n0 = 64 * w + j;
            const _Float16* bi0 = wihR + (size_t)(n0     ) * 512 + kof;
            const _Float16* bi1 = wihR + (size_t)(n0 + 16) * 512 + kof;
            const _Float16* bi2 = wihR + (size_t)(n0 + 32) * 512 + kof;
            const _Float16* bi3 = wihR + (size_t)(n0 + 48) * 512 + kof;
            const _Float16* bh0 = whhR + (size_t)(n0     ) * 512 + kof;
            const _Float16* bh1 = whhR + (size_t)(n0 + 16) * 512 + kof;
            const _Float16* bh2 = whhR + (size_t)(n0 + 32) * 512 + kof;
            const _Float16* bh3 = whhR + (size_t)(n0 + 48) * 512 + kof;
            #pragma unroll
            for (int ks = 0; ks < 16; ++ks) {
                const int o = ks * 32;
                f16x8 ax = *(const f16x8*)(xa + o);
                f16x8 ah = *(const f16x8*)(ha + o);
                g0 = MFMA(ax, *(const f16x8*)(bi0 + o), g0);
                g0 = MFMA(ah, *(const f16x8*)(bh0 + o), g0);
                g1 = MFMA(ax, *(const f16x8*)(bi1 + o), g1);
                g1 = MFMA(ah, *(const f16x8*)(bh1 + o), g1);
                g2 = MFMA(ax, *(const f16x8*)(bi2 + o), g2);
                g2 = MFMA(ah, *(const f16x8*)(bh2 + o), g2);
                g3 = MFMA(ax, *(const f16x8*)(bi3 + o), g3);
                g3 = MFMA(ah, *(const f16x8*)(bh3 + o), g3);
            }
        }
        // stash pre-activations (+bias) in LDS, redistribute to (row, h-col) owners
        {
            #pragma unroll
            for (int r = 0; r < 4; ++r) {
                const int row = erow0 + r;
                glds[row * 64 + j     ] = g0[r] + gbias[0];
                glds[row * 64 + j + 16] = g1[r] + gbias[1];
                glds[row * 64 + j + 32] = g2[r] + gbias[2];
                glds[row * 64 + j + 48] = g3[r] + gbias[3];
            }
        }
        __syncthreads();
        #pragma unroll
        for (int r = 0; r < 4; ++r) {
            const int row = prow0 + r;
            const float ig = sigf (glds[row * 64 + pj]);
            const float fg = sigf (glds[row * 64 + 16 + pj]);
            const float gg = tanhf(glds[row * 64 + 32 + pj]);
            const float og = sigf (glds[row * 64 + 48 + pj]);
            const float cn = fg * creg[r] + ig * gg;
            creg[r] = cn;
            const float hn = og * tanhf(cn);
            h32[row * HID + pcol] = hn;
            ho[row * HID + pcol] = (_Float16)hn;
            if (pool == 0) ring[(t & 3) * BH + row * HID + pcol] = hn;
            else           out[(size_t)t * BH + row * HID + pcol] = hn;
            if (t == SEQ - 1) {
                out[OUT_H + pool * BH + row * HID + pcol] = hn;
                out[OUT_C + pool * BH + row * HID + pcol] = cn;
            }
        }
        __syncthreads();          // glds reuse safety for next step
        wg_signal(&cntP[t * 6 + 5]);
    }
}

// ---------------- host launch ----------------
extern "C" void kernel_launch(void* const* d_in, const int* in_sizes, int n_in,
                              void* d_out, int out_size, void* d_ws, size_t ws_size,
                              hipStream_t stream) {
    const float* in_seq  = (const float*)d_in[0];
    const float* l1_mogW = (const float*)d_in[1];
    const float* l1_mogb = (const float*)d_in[2];
    const float* l1_Wih  = (const float*)d_in[3];
    const float* l1_Whh  = (const float*)d_in[4];
    const float* l1_bih  = (const float*)d_in[5];
    const float* l1_bhh  = (const float*)d_in[6];
    const float* l2_mogW = (const float*)d_in[7];
    const float* l2_mogb = (const float*)d_in[8];
    const float* l2_Wih  = (const float*)d_in[9];
    const float* l2_Whh  = (const float*)d_in[10];
    const float* l2_bih  = (const float*)d_in[11];
    const float* l2_bhh  = (const float*)d_in[12];

    hipMemsetAsync(d_ws, 0, ZERO_PREFIX, stream);

    prologue_convert<<<256, 256, 0, stream>>>(l1_mogW, l1_Wih, l1_Whh,
                                              l2_mogW, l2_Wih, l2_Whh, (char*)d_ws);

    moglstm_persist<<<64, NTHR, 98304, stream>>>(in_seq, l1_mogb, l2_mogb,
                                                 l1_bih, l1_bhh, l2_bih, l2_bhh,
                                                 (float*)d_out, (char*)d_ws);
}

// Round 7
// 17432.893 us; speedup vs baseline: 5.8735x; 1.9660x over previous
//
#include <hip/hip_runtime.h>
#include <cstdint>

// ---------------- problem constants ----------------
#define SEQ   512
#define BATCH 64
#define HID   512
#define BH    (BATCH*HID)
#define NWGP  32                   // workgroups per pool
#define NTHR  256                  // 4 waves

#define MOG_ELEMS   (5*512*512)                  // 1310720
#define GATE_ELEMS  (2048*512)                   // 1048576
#define LAYER_ELEMS (MOG_ELEMS + 2*GATE_ELEMS)   // 3407872

// ---------------- ws layout (bytes) ----------------
// flags[pool][phase][w]: one 128B line per (pool,phase)
#define WS_FLG   0                 // 2*6*32*4 = 1536
#define WS_H16   4096              // 2 pools * 2 bufs * 32*64*16 f16 = 262144
#define ZERO_PREFIX 266240         // flags + h16
#define WS_X16   266240            // 2 pools * 32*64*16 f16 = 131072
#define WS_RING  397312            // 4 slots * 32*64*16 f32 = 524288
#define WS_WT    921600            // 2 layers * LAYER_ELEMS * 2B = 13631488 (end 14553088)

// d_out layout (floats)
#define OUT_H 16777216             // last_hidden [2,64,512]
#define OUT_C 16842752             // last_cell   [2,64,512]

typedef _Float16 f16x8 __attribute__((ext_vector_type(8)));
typedef float    f32x4 __attribute__((ext_vector_type(4)));

#define MFMA(a,b,c) __builtin_amdgcn_mfma_f32_16x16x32_f16((a),(b),(c),0,0,0)

// ---------------- coherence-point (bypass L1+L2) coalesced access ----------------
// Plain non-atomic sc0sc1 ops: write-through / read-through the per-XCD caches.
// NO buffer_inv, NO wbL2 anywhere in this kernel.
#define GLD16(dst, ptr) \
    asm volatile("global_load_dwordx4 %0, %1, off sc0 sc1" : "=v"(dst) : "v"(ptr))
#define GLDF(dst, ptr) \
    asm volatile("global_load_dword %0, %1, off sc0 sc1" : "=v"(dst) : "v"(ptr))
#define GST16(ptr, val) \
    asm volatile("global_store_dwordx4 %0, %1, off sc0 sc1" :: "v"(ptr), "v"(val) : "memory")
#define FLAGST(ptr, val) \
    asm volatile("global_store_dword %0, %1, off sc0 sc1" :: "v"(ptr), "v"(val) : "memory")
#define VMWAIT() asm volatile("s_waitcnt vmcnt(0)" ::: "memory")

__device__ __forceinline__ float sigf(float z) { return 1.f / (1.f + __expf(-z)); }

// wave-parallel flag poll: lanes of wave 0 each watch one producer's tag dword
// (single coalesced 128B-line load per iteration); monotonic tags, compare >=.
__device__ __forceinline__ void poll_ge(const unsigned* line, unsigned tag) {
    if (threadIdx.x < 64) {
        const unsigned* p = line + (threadIdx.x & 31);
        for (;;) {
            unsigned v;
            asm volatile("global_load_dword %0, %1, off sc0 sc1\n\ts_waitcnt vmcnt(0)"
                         : "=v"(v) : "v"(p) : "memory");
            if (__ballot(v >= tag) == ~0ull) break;
        }
    }
    __syncthreads();
}

// Reordered gate layout: rg = 64*b + 16*gate + j  <->  orig row = gate*512 + 16*b + j
__device__ __forceinline__ int gate_orig_row(int rg) {
    return ((rg >> 4) & 3) * 512 + ((rg >> 6) << 4) + (rg & 15);
}

// ---------------- prologue: f32 -> f16 weight conversion + gate reorder --------
__global__ __launch_bounds__(256)
void prologue_convert(const float* __restrict__ l1_mogW, const float* __restrict__ l1_Wih,
                      const float* __restrict__ l1_Whh,
                      const float* __restrict__ l2_mogW, const float* __restrict__ l2_Wih,
                      const float* __restrict__ l2_Whh,  char* __restrict__ ws)
{
    _Float16* wdst = (_Float16*)(ws + WS_WT);
    const int total = 2 * LAYER_ELEMS;
    const int stride = gridDim.x * blockDim.x;
    for (int idx = blockIdx.x * blockDim.x + threadIdx.x; idx < total; idx += stride) {
        const int layer = idx >= LAYER_ELEMS;
        const int r = idx - layer * LAYER_ELEMS;
        float v;
        if (r < MOG_ELEMS) {
            v = (layer ? l2_mogW : l1_mogW)[r];
        } else {
            const int q = r - MOG_ELEMS;
            const int mat = q >= GATE_ELEMS;          // 0 = Wih, 1 = Whh
            const int e = q - mat * GATE_ELEMS;
            const int rg = e >> 9;
            const int k  = e & 511;
            const int orig = gate_orig_row(rg);
            const float* W = mat ? (layer ? l2_Whh : l1_Whh)
                                 : (layer ? l2_Wih : l1_Wih);
            v = W[orig * 512 + k];
        }
        wdst[idx] = (_Float16)v;
    }
}

// ---------------- persistent kernel ----------------
// grid = 64 x 256. Pool 0 = blocks 0..31 (layer 1), pool 1 = layer 2.
// WG w owns cols [16w,16w+16). Wave wv owns rows [16wv,16wv+16).
// Activation exchange: slice-major [slice][row 64][col 16] f16 buffers, written
// by LDS-transpose + coalesced 16B sc0sc1 stores, read by coalesced 16B sc0sc1
// loads. Weights/in_seq/bias: normal cached path, never invalidated (no acquire
// exists). Masters x,h,c: registers. Mog weights: LDS.
__global__ __launch_bounds__(NTHR, 1)
void moglstm_persist(const float* __restrict__ in_seq,
                     const float* __restrict__ mogb1, const float* __restrict__ mogb2,
                     const float* __restrict__ bih1,  const float* __restrict__ bhh1,
                     const float* __restrict__ bih2,  const float* __restrict__ bhh2,
                     float* __restrict__ out, char* __restrict__ ws)
{
    const int pool = blockIdx.x >> 5;
    const int w    = blockIdx.x & 31;
    const int tid  = threadIdx.x;
    const int lane = tid & 63;
    const int wv   = tid >> 6;

    extern __shared__ char smem[];
    _Float16* wlds = (_Float16*)smem;                 // [5][16][512] swizzled, 80 KB
    _Float16* hbuf = (_Float16*)(smem + 81920);       // [64][24] f16 transpose buf, 3 KB
    float*    fbuf = (float*)(smem + 84992);          // [64][20] f32 transpose buf, 5 KB

    unsigned* flg     = (unsigned*)(ws + WS_FLG);
    unsigned* myline  = flg + (pool * 6) * 32;        // + p*32 per phase
    unsigned* othline = flg + ((1 - pool) * 6) * 32;

    _Float16* h16 = (_Float16*)(ws + WS_H16) + pool * (2 * BH);   // [2][32][64][16]
    _Float16* x16 = (_Float16*)(ws + WS_X16) + pool * BH;         // [32][64][16]
    float*    ring = (float*)(ws + WS_RING);                      // [4][32][64][16]
    const _Float16* Wb   = (const _Float16*)(ws + WS_WT) + (size_t)pool * LAYER_ELEMS;
    const _Float16* mogW = Wb;
    const _Float16* wihR = Wb + MOG_ELEMS;
    const _Float16* whhR = wihR + GATE_ELEMS;
    const float* mogb = pool ? mogb2 : mogb1;
    const float* bih  = pool ? bih2 : bih1;
    const float* bhh  = pool ? bhh2 : bhh1;

    const int j     = lane & 15;
    const int hi    = lane >> 4;
    const int kof   = hi * 8;
    const int arow  = 16 * wv + j;        // A row (m)
    const int erow0 = 16 * wv + 4 * hi;   // C/D row base
    const int ecol  = 16 * w + j;         // global output col
    const int cxor  = (j & 7) << 3;
    // per-thread A-load base offset within a slice-major activation buffer (elems)
    const int aoff  = (hi >> 1) * 1024 + arow * 16 + (hi & 1) * 8;

    // ---- stage mog weights into LDS (R6-verified layout) ----
    for (int i = tid; i < 5 * 16 * 64; i += NTHR) {
        const int p   = i >> 10;
        const int rem = i & 1023;
        const int c   = rem >> 6;
        const int k   = (rem & 63) << 3;
        f16x8 v = *(const f16x8*)(mogW + ((size_t)p * 512 + 16 * w + c) * 512 + k);
        *(f16x8*)&wlds[((p * 16 + c) << 9) + (k ^ ((c & 7) << 3))] = v;
    }
    __syncthreads();

    // biases hoisted
    float mb[5];
    #pragma unroll
    for (int p = 0; p < 5; ++p) mb[p] = mogb[p * 512 + ecol];
    float gbias[4];
    #pragma unroll
    for (int g = 0; g < 4; ++g) gbias[g] = bih[g * 512 + ecol] + bhh[g * 512 + ecol];

    float xreg[4];
    float hreg[4] = {0.f, 0.f, 0.f, 0.f};
    float creg[4] = {0.f, 0.f, 0.f, 0.f};

    for (int t = 0; t < SEQ; ++t) {
        _Float16* hb = h16 + (t & 1) * BH;          // h during step t
        _Float16* ho = h16 + ((t & 1) ^ 1) * BH;    // next-step h (gates output)

        // prefetch in_seq rows (flag-independent, hides under the p0 poll)
        float xseq[4];
        if (pool == 0) {
            #pragma unroll
            for (int r = 0; r < 4; ++r)
                xseq[r] = in_seq[(size_t)t * BH + (erow0 + r) * HID + ecol];
        }

        // ---------------- mogrifier phases 0..4 ----------------
        #pragma unroll
        for (int p = 0; p < 5; ++p) {
            if (p == 0) {
                if (t > 0) poll_ge(myline + 5 * 32, 6u * (t - 1) + 6);   // own gates(t-1)
                if (pool == 1) poll_ge(othline + 5 * 32, 6u * t + 6);    // h1[t] in ring
            } else {
                poll_ge(myline + (p - 1) * 32, 6u * t + p);
            }

            const _Float16* act = (p & 1) ? x16 : hb;   // even: A=h; odd: A=x

            // ring loads (pool1 p0: own slice, slice-major f32)
            float rv[4];
            if (p == 0 && pool == 1) {
                const float* rp = ring + (t & 3) * BH + w * 1024 + erow0 * 16 + j;
                GLDF(rv[0], rp); GLDF(rv[1], rp + 16); GLDF(rv[2], rp + 32); GLDF(rv[3], rp + 48);
            }
            // A-matrix: 16 coalesced 16B loads from coherence point
            f16x8 a[16];
            {
                const _Float16* ab = act + aoff;
                #pragma unroll
                for (int ks = 0; ks < 16; ++ks) GLD16(a[ks], ab + ks * 2048);
            }
            VMWAIT();
            __builtin_amdgcn_sched_barrier(0);

            const _Float16* wl = wlds + ((p * 16 + j) << 9);
            f32x4 acc = {0.f, 0.f, 0.f, 0.f};
            #pragma unroll
            for (int ks = 0; ks < 16; ++ks)
                acc = MFMA(a[ks], *(const f16x8*)&wl[(kof + ks * 32) ^ cxor], acc);

            // epilogue: update register master
            float nv[4];
            #pragma unroll
            for (int r = 0; r < 4; ++r) {
                const float s = 2.f * sigf(acc[r] + mb[p]);
                if ((p & 1) == 0) {
                    const float xo = (p == 0) ? ((pool == 0) ? xseq[r] : rv[r]) : xreg[r];
                    nv[r] = s * xo;  xreg[r] = nv[r];
                } else {
                    nv[r] = s * hreg[r];  hreg[r] = nv[r];
                }
            }
            // publish slice: LDS transpose -> coalesced 16B sc0sc1 stores
            _Float16* target = ((p & 1) == 0) ? x16 : hb;
            #pragma unroll
            for (int r = 0; r < 4; ++r) hbuf[(erow0 + r) * 24 + j] = (_Float16)nv[r];
            __syncthreads();
            if (tid < 128) {
                const int row = tid >> 1, c8 = (tid & 1) * 8;
                f16x8 v = *(const f16x8*)&hbuf[row * 24 + c8];
                GST16(target + w * 1024 + row * 16 + c8, v);
            }
            VMWAIT();                       // store-ack at coherence point
            __syncthreads();
            if (tid == 0) FLAGST(myline + p * 32 + w, 6u * t + p + 1);
        }

        // ---------------- LSTM gates ----------------
        poll_ge(myline + 4 * 32, 6u * t + 5);
        if (pool == 0 && t >= 4) poll_ge(othline + 0 * 32, 6u * (t - 4) + 1);  // ring credit

        f16x8 ax[16], ah[16];
        {
            const _Float16* xb = x16 + aoff;
            const _Float16* hB = hb  + aoff;
            #pragma unroll
            for (int ks = 0; ks < 16; ++ks) { GLD16(ax[ks], xb + ks * 2048); GLD16(ah[ks], hB + ks * 2048); }
        }
        VMWAIT();
        __builtin_amdgcn_sched_barrier(0);

        f32x4 g0 = {0,0,0,0}, g1 = {0,0,0,0}, g2 = {0,0,0,0}, g3 = {0,0,0,0};
        {
            const int n0 = 64 * w + j;
            const _Float16* bi0 = wihR + (size_t)(n0     ) * 512 + kof;
            const _Float16* bi1 = wihR + (size_t)(n0 + 16) * 512 + kof;
            const _Float16* bi2 = wihR + (size_t)(n0 + 32) * 512 + kof;
            const _Float16* bi3 = wihR + (size_t)(n0 + 48) * 512 + kof;
            const _Float16* bh0 = whhR + (size_t)(n0     ) * 512 + kof;
            const _Float16* bh1 = whhR + (size_t)(n0 + 16) * 512 + kof;
            const _Float16* bh2 = whhR + (size_t)(n0 + 32) * 512 + kof;
            const _Float16* bh3 = whhR + (size_t)(n0 + 48) * 512 + kof;
            #pragma unroll
            for (int ks = 0; ks < 16; ++ks) {
                const int o = ks * 32;
                g0 = MFMA(ax[ks], *(const f16x8*)(bi0 + o), g0);
                g0 = MFMA(ah[ks], *(const f16x8*)(bh0 + o), g0);
                g1 = MFMA(ax[ks], *(const f16x8*)(bi1 + o), g1);
                g1 = MFMA(ah[ks], *(const f16x8*)(bh1 + o), g1);
                g2 = MFMA(ax[ks], *(const f16x8*)(bi2 + o), g2);
                g2 = MFMA(ah[ks], *(const f16x8*)(bh2 + o), g2);
                g3 = MFMA(ax[ks], *(const f16x8*)(bi3 + o), g3);
                g3 = MFMA(ah[ks], *(const f16x8*)(bh3 + o), g3);
            }
        }
        // epilogue: thread already owns all 4 gates of its cells (n0 = 64w+j)
        float hnv[4], cnv[4];
        #pragma unroll
        for (int r = 0; r < 4; ++r) {
            const float ig = sigf (g0[r] + gbias[0]);
            const float fg = sigf (g1[r] + gbias[1]);
            const float gg = tanhf(g2[r] + gbias[2]);
            const float og = sigf (g3[r] + gbias[3]);
            const float cn = fg * creg[r] + ig * gg;
            creg[r] = cn;  cnv[r] = cn;
            const float hn = og * tanhf(cn);
            hreg[r] = hn;  hnv[r] = hn;
        }
        // publish: ho slice (f16) + ring slice (f32, pool0) / out rows (pool1)
        #pragma unroll
        for (int r = 0; r < 4; ++r) hbuf[(erow0 + r) * 24 + j] = (_Float16)hnv[r];
        if (pool == 0) {
            #pragma unroll
            for (int r = 0; r < 4; ++r) fbuf[(erow0 + r) * 20 + j] = hnv[r];
        } else {
            #pragma unroll
            for (int r = 0; r < 4; ++r)
                out[(size_t)t * BH + (erow0 + r) * HID + ecol] = hnv[r];
        }
        if (t == SEQ - 1) {
            #pragma unroll
            for (int r = 0; r < 4; ++r) {
                out[OUT_H + pool * BH + (erow0 + r) * HID + ecol] = hnv[r];
                out[OUT_C + pool * BH + (erow0 + r) * HID + ecol] = cnv[r];
            }
        }
        __syncthreads();
        if (tid < 128) {
            const int row = tid >> 1, c8 = (tid & 1) * 8;
            f16x8 v = *(const f16x8*)&hbuf[row * 24 + c8];
            GST16(ho + w * 1024 + row * 16 + c8, v);
        }
        if (pool == 0) {
            const int row = tid >> 2, c4 = (tid & 3) * 4;
            f32x4 v = *(const f32x4*)&fbuf[row * 20 + c4];
            GST16(ring + (t & 3) * BH + w * 1024 + row * 16 + c4, v);
        }
        VMWAIT();
        __syncthreads();
        if (tid == 0) FLAGST(myline + 5 * 32 + w, 6u * t + 6);
    }
}

// ---------------- host launch ----------------
extern "C" void kernel_launch(void* const* d_in, const int* in_sizes, int n_in,
                              void* d_out, int out_size, void* d_ws, size_t ws_size,
                              hipStream_t stream) {
    const float* in_seq  = (const float*)d_in[0];
    const float* l1_mogW = (const float*)d_in[1];
    const float* l1_mogb = (const float*)d_in[2];
    const float* l1_Wih  = (const float*)d_in[3];
    const float* l1_Whh  = (const float*)d_in[4];
    const float* l1_bih  = (const float*)d_in[5];
    const float* l1_bhh  = (const float*)d_in[6];
    const float* l2_mogW = (const float*)d_in[7];
    const float* l2_mogb = (const float*)d_in[8];
    const float* l2_Wih  = (const float*)d_in[9];
    const float* l2_Whh  = (const float*)d_in[10];
    const float* l2_bih  = (const float*)d_in[11];
    const float* l2_bhh  = (const float*)d_in[12];

    hipMemsetAsync(d_ws, 0, ZERO_PREFIX, stream);

    prologue_convert<<<256, 256, 0, stream>>>(l1_mogW, l1_Wih, l1_Whh,
                                              l2_mogW, l2_Wih, l2_Whh, (char*)d_ws);

    moglstm_persist<<<64, NTHR, 90112, stream>>>(in_seq, l1_mogb, l2_mogb,
                                                 l1_bih, l1_bhh, l2_bih, l2_bhh,
                                                 (float*)d_out, (char*)d_ws);
}

// Round 9
// 16161.563 us; speedup vs baseline: 6.3355x; 1.0787x over previous
//
#include <hip/hip_runtime.h>
#include <cstdint>

// ---------------- problem constants ----------------
#define SEQ   512
#define BATCH 64
#define HID   512
#define BH    (BATCH*HID)
#define NWGP  32                   // workgroups per pool
#define NTHR  256                  // 4 waves

#define MOG_ELEMS   (5*512*512)                  // 1310720
#define GATE_ELEMS  (2048*512)                   // 1048576
#define LAYER_ELEMS (MOG_ELEMS + 2*GATE_ELEMS)   // 3407872

// ---------------- ws layout (bytes) ----------------
// flags: [pool][phase] lines of 32 tags, 64B stride each (512 dwords/line)
#define WS_FLG   0                 // 2*6*512*4 = 24576
#define WS_H16   24576             // 2 pools * 2 bufs * 32*64*16 f16 = 262144
#define ZERO_PREFIX 286720         // flags + h16
#define WS_X16   286720            // 131072
#define WS_RING  417792            // 4 slots * BH * 4B = 524288
#define WS_WT    942080            // 2 layers * LAYER_ELEMS * 2B = 13631488 (end 14573568)

// d_out layout (floats)
#define OUT_H 16777216
#define OUT_C 16842752

typedef _Float16 f16x8 __attribute__((ext_vector_type(8)));
typedef float    f32x4 __attribute__((ext_vector_type(4)));

#define MFMA(a,b,c) __builtin_amdgcn_mfma_f32_16x16x32_f16((a),(b),(c),0,0,0)

// ---------------- coherence-point (IC) coalesced access (R7-proven) ----------------
#define GLD16(dst, ptr) \
    asm volatile("global_load_dwordx4 %0, %1, off sc0 sc1" : "=v"(dst) : "v"(ptr))
#define GLDF(dst, ptr) \
    asm volatile("global_load_dword %0, %1, off sc0 sc1" : "=v"(dst) : "v"(ptr))
#define GST16(ptr, val) \
    asm volatile("global_store_dwordx4 %0, %1, off sc0 sc1" :: "v"(ptr), "v"(val) : "memory")
#define FLAGST(ptr, val) \
    asm volatile("global_store_dword %0, %1, off sc0 sc1" :: "v"(ptr), "v"(val) : "memory")
#define VMWAIT() asm volatile("s_waitcnt vmcnt(0)" ::: "memory")
#define TIE(x)   asm volatile("" : "+v"(x))
// tag load + wait-all (drains the whole speculative batch)
#define TAGLDW(dst, ptr) \
    asm volatile("global_load_dword %0, %1, off sc0 sc1\n\ts_waitcnt vmcnt(0)" \
                 : "=v"(dst) : "v"(ptr) : "memory")

__device__ __forceinline__ float sigf(float z) { return 1.f / (1.f + __expf(-z)); }

// Reordered gate layout: rg = 64*b + 16*gate + j  <->  orig row = gate*512 + 16*b + j
__device__ __forceinline__ int gate_orig_row(int rg) {
    return ((rg >> 4) & 3) * 512 + ((rg >> 6) << 4) + (rg & 15);
}

// ---------------- prologue: f32 -> f16 weight conversion + gate reorder --------
__global__ __launch_bounds__(256)
void prologue_convert(const float* __restrict__ l1_mogW, const float* __restrict__ l1_Wih,
                      const float* __restrict__ l1_Whh,
                      const float* __restrict__ l2_mogW, const float* __restrict__ l2_Wih,
                      const float* __restrict__ l2_Whh,  char* __restrict__ ws)
{
    _Float16* wdst = (_Float16*)(ws + WS_WT);
    const int total = 2 * LAYER_ELEMS;
    const int stride = gridDim.x * blockDim.x;
    for (int idx = blockIdx.x * blockDim.x + threadIdx.x; idx < total; idx += stride) {
        const int layer = idx >= LAYER_ELEMS;
        const int r = idx - layer * LAYER_ELEMS;
        float v;
        if (r < MOG_ELEMS) {
            v = (layer ? l2_mogW : l1_mogW)[r];
        } else {
            const int q = r - MOG_ELEMS;
            const int mat = q >= GATE_ELEMS;
            const int e = q - mat * GATE_ELEMS;
            const int rg = e >> 9;
            const int k  = e & 511;
            const int orig = gate_orig_row(rg);
            const float* W = mat ? (layer ? l2_Whh : l1_Whh)
                                 : (layer ? l2_Wih : l1_Wih);
            v = W[orig * 512 + k];
        }
        wdst[idx] = (_Float16)v;
    }
}

// ---------------- persistent kernel ----------------
// grid = 64 x 256. Pool 0 = blocks 0..31 (layer 1), pool 1 = layer 2.
// WG w owns cols [16w,16w+16). Wave wv owns rows [16wv,16wv+16).
// Data plane: R7-proven (slice-major sc0sc1 buffers, LDS-transposed 16B publishes).
// NEW: per-wave speculative tag+data poll (accept on prev-iteration tag — data is
// in registers at accept, removing the post-detect load RT); gates h-side MFMAs
// prefused into phase 4's tail; 64B-stride flags.
__global__ __launch_bounds__(NTHR, 1)
void moglstm_persist(const float* __restrict__ in_seq,
                     const float* __restrict__ mogb1, const float* __restrict__ mogb2,
                     const float* __restrict__ bih1,  const float* __restrict__ bhh1,
                     const float* __restrict__ bih2,  const float* __restrict__ bhh2,
                     float* __restrict__ out, char* __restrict__ ws)
{
    const int pool = blockIdx.x >> 5;
    const int w    = blockIdx.x & 31;
    const int tid  = threadIdx.x;
    const int lane = tid & 63;
    const int wv   = tid >> 6;

    extern __shared__ char smem[];
    _Float16* wlds = (_Float16*)smem;                 // [5][16][512] swizzled, 80 KB
    _Float16* hbuf = (_Float16*)(smem + 81920);       // [64][24] f16 transpose buf
    float*    fbuf = (float*)(smem + 84992);          // [64][20] f32 transpose buf

    unsigned* flg = (unsigned*)(ws + WS_FLG);         // line(pool,ph) = (pool*6+ph)*512 dw

    _Float16* h16 = (_Float16*)(ws + WS_H16) + pool * (2 * BH);   // [2][32][64][16]
    _Float16* x16 = (_Float16*)(ws + WS_X16) + pool * BH;         // [32][64][16]
    float*    ring = (float*)(ws + WS_RING);                      // [4][32][64][16]
    const _Float16* Wb   = (const _Float16*)(ws + WS_WT) + (size_t)pool * LAYER_ELEMS;
    const _Float16* mogW = Wb;
    const _Float16* wihR = Wb + MOG_ELEMS;
    const _Float16* whhR = wihR + GATE_ELEMS;
    const float* mogb = pool ? mogb2 : mogb1;
    const float* bih  = pool ? bih2 : bih1;
    const float* bhh  = pool ? bhh2 : bhh1;

    const int j     = lane & 15;
    const int hi    = lane >> 4;
    const int kof   = hi * 8;
    const int arow  = 16 * wv + j;
    const int erow0 = 16 * wv + 4 * hi;
    const int ecol  = 16 * w + j;
    const int cxor  = (j & 7) << 3;
    const int aoff  = (hi >> 1) * 1024 + arow * 16 + (hi & 1) * 8;

    // gate weight streams (cached path)
    const int n0 = 64 * w + j;
    const _Float16* bi0 = wihR + (size_t)(n0     ) * 512 + kof;
    const _Float16* bi1 = wihR + (size_t)(n0 + 16) * 512 + kof;
    const _Float16* bi2 = wihR + (size_t)(n0 + 32) * 512 + kof;
    const _Float16* bi3 = wihR + (size_t)(n0 + 48) * 512 + kof;
    const _Float16* bh0 = whhR + (size_t)(n0     ) * 512 + kof;
    const _Float16* bh1 = whhR + (size_t)(n0 + 16) * 512 + kof;
    const _Float16* bh2 = whhR + (size_t)(n0 + 32) * 512 + kof;
    const _Float16* bh3 = whhR + (size_t)(n0 + 48) * 512 + kof;

    // ---- stage mog weights into LDS (invalidate-free cached reads) ----
    for (int i = tid; i < 5 * 16 * 64; i += NTHR) {
        const int p   = i >> 10;
        const int rem = i & 1023;
        const int c   = rem >> 6;
        const int k   = (rem & 63) << 3;
        f16x8 v = *(const f16x8*)(mogW + ((size_t)p * 512 + 16 * w + c) * 512 + k);
        *(f16x8*)&wlds[((p * 16 + c) << 9) + (k ^ ((c & 7) << 3))] = v;
    }
    __syncthreads();

    float mb[5];
    #pragma unroll
    for (int p = 0; p < 5; ++p) mb[p] = mogb[p * 512 + ecol];
    float gbias[4];
    #pragma unroll
    for (int g = 0; g < 4; ++g) gbias[g] = bih[g * 512 + ecol] + bhh[g * 512 + ecol];

    float xreg[4];
    float hreg[4] = {0.f, 0.f, 0.f, 0.f};
    float creg[4] = {0.f, 0.f, 0.f, 0.f};
    f16x8 a[16];                          // speculative A-batch (reused per phase)

    for (int t = 0; t < SEQ; ++t) {
        _Float16* hb = h16 + (t & 1) * BH;
        _Float16* ho = h16 + ((t & 1) ^ 1) * BH;
        f32x4 g0 = {0,0,0,0}, g1 = {0,0,0,0}, g2 = {0,0,0,0}, g3 = {0,0,0,0};

        float xseq[4];
        if (pool == 0) {
            #pragma unroll
            for (int r = 0; r < 4; ++r)
                xseq[r] = in_seq[(size_t)t * BH + (erow0 + r) * HID + ecol];
        }

        // ---------------- mogrifier phases 0..4 ----------------
        #pragma unroll
        for (int p = 0; p < 5; ++p) {
            // ---- speculative tag+data accept (per-wave) ----
            const unsigned* prim = flg + (size_t)(pool * 6 + ((p == 0) ? 5 : p - 1)) * 512;
            const unsigned* sec  = prim;
            unsigned ptgt = 6u * (unsigned)t + (unsigned)p;     // p==0 -> 6t (gates t-1)
            unsigned stgt = ptgt;
            if (p == 0 && pool == 1) { sec = flg + (size_t)5 * 512; stgt = 6u * t + 6u; }
            const unsigned* tp = (lane < 32) ? (prim + lane * 16) : (sec + (lane - 32) * 16);
            const unsigned mytgt = (lane < 32) ? ptgt : stgt;

            const _Float16* act = (p & 1) ? x16 : hb;
            const _Float16* ab  = act + aoff;
            const float* rp = ring + (t & 3) * BH + w * 1024 + erow0 * 16 + j;
            float rv[4];
            bool prev_ok = false;
            for (;;) {
                if (p == 0 && pool == 1) {
                    GLDF(rv[0], rp); GLDF(rv[1], rp + 16); GLDF(rv[2], rp + 32); GLDF(rv[3], rp + 48);
                }
                #pragma unroll
                for (int ks = 0; ks < 16; ++ks) GLD16(a[ks], ab + ks * 2048);
                unsigned tagv;
                TAGLDW(tagv, tp);                        // waits the whole batch
                if (prev_ok) break;                      // current batch issued after tags seen
                prev_ok = (__ballot(tagv >= mytgt) == ~0ull);
            }
            #pragma unroll
            for (int ks = 0; ks < 16; ++ks) TIE(a[ks]);
            if (p == 0 && pool == 1) { TIE(rv[0]); TIE(rv[1]); TIE(rv[2]); TIE(rv[3]); }
            __builtin_amdgcn_sched_barrier(0);

            // ---- MFMA (B from LDS) ----
            const _Float16* wl = wlds + ((p * 16 + j) << 9);
            f32x4 acc = {0.f, 0.f, 0.f, 0.f};
            #pragma unroll
            for (int ks = 0; ks < 16; ++ks)
                acc = MFMA(a[ks], *(const f16x8*)&wl[(kof + ks * 32) ^ cxor], acc);

            // ---- epilogue: register masters ----
            float nv[4];
            #pragma unroll
            for (int r = 0; r < 4; ++r) {
                const float s = 2.f * sigf(acc[r] + mb[p]);
                if ((p & 1) == 0) {
                    const float xo = (p == 0) ? ((pool == 0) ? xseq[r] : rv[r]) : xreg[r];
                    nv[r] = s * xo;  xreg[r] = nv[r];
                } else {
                    nv[r] = s * hreg[r];  hreg[r] = nv[r];
                }
            }
            // ---- publish slice (LDS transpose -> coalesced 16B sc0sc1) ----
            _Float16* target = ((p & 1) == 0) ? x16 : hb;
            #pragma unroll
            for (int r = 0; r < 4; ++r) hbuf[(erow0 + r) * 24 + j] = (_Float16)nv[r];
            __syncthreads();
            if (tid < 128) {
                const int row = tid >> 1, c8 = (tid & 1) * 8;
                f16x8 v = *(const f16x8*)&hbuf[row * 24 + c8];
                GST16(target + w * 1024 + row * 16 + c8, v);
            }
            VMWAIT();
            __syncthreads();
            if (tid == 0) FLAGST(flg + (size_t)(pool * 6 + p) * 512 + w * 16, 6u * t + p + 1);

            // ---- p4 tail: prefuse gates h-side (a[] still holds h3 fragments) ----
            if (p == 4) {
                #pragma unroll
                for (int ks = 0; ks < 16; ++ks) {
                    const int o = ks * 32;
                    g0 = MFMA(a[ks], *(const f16x8*)(bh0 + o), g0);
                    g1 = MFMA(a[ks], *(const f16x8*)(bh1 + o), g1);
                    g2 = MFMA(a[ks], *(const f16x8*)(bh2 + o), g2);
                    g3 = MFMA(a[ks], *(const f16x8*)(bh3 + o), g3);
                }
            }
        }

        // ---------------- LSTM gates (x-side only; h-side prefused) ----------------
        {
            const unsigned* prim = flg + (size_t)(pool * 6 + 4) * 512;
            const unsigned* sec  = prim;
            unsigned ptgt = 6u * t + 5u;
            unsigned stgt = ptgt;
            if (pool == 0) { sec = flg + (size_t)(6 + 0) * 512;           // pool1 p0 line
                             stgt = (t >= 4) ? (6u * (t - 4) + 1u) : 0u; } // ring credit
            const unsigned* tp = (lane < 32) ? (prim + lane * 16) : (sec + (lane - 32) * 16);
            const unsigned mytgt = (lane < 32) ? ptgt : stgt;

            const _Float16* ab = x16 + aoff;
            bool prev_ok = false;
            for (;;) {
                #pragma unroll
                for (int ks = 0; ks < 16; ++ks) GLD16(a[ks], ab + ks * 2048);
                unsigned tagv;
                TAGLDW(tagv, tp);
                if (prev_ok) break;
                prev_ok = (__ballot(tagv >= mytgt) == ~0ull);
            }
            #pragma unroll
            for (int ks = 0; ks < 16; ++ks) TIE(a[ks]);
            __builtin_amdgcn_sched_barrier(0);

            #pragma unroll
            for (int ks = 0; ks < 16; ++ks) {
                const int o = ks * 32;
                g0 = MFMA(a[ks], *(const f16x8*)(bi0 + o), g0);
                g1 = MFMA(a[ks], *(const f16x8*)(bi1 + o), g1);
                g2 = MFMA(a[ks], *(const f16x8*)(bi2 + o), g2);
                g3 = MFMA(a[ks], *(const f16x8*)(bi3 + o), g3);
            }
        }

        // ---- gate epilogue (thread owns all 4 gates of its cells) ----
        float hnv[4], cnv[4];
        #pragma unroll
        for (int r = 0; r < 4; ++r) {
            const float ig = sigf (g0[r] + gbias[0]);
            const float fg = sigf (g1[r] + gbias[1]);
            const float gg = tanhf(g2[r] + gbias[2]);
            const float og = sigf (g3[r] + gbias[3]);
            const float cn = fg * creg[r] + ig * gg;
            creg[r] = cn;  cnv[r] = cn;
            const float hn = og * tanhf(cn);
            hreg[r] = hn;  hnv[r] = hn;
        }
        #pragma unroll
        for (int r = 0; r < 4; ++r) hbuf[(erow0 + r) * 24 + j] = (_Float16)hnv[r];
        if (pool == 0) {
            #pragma unroll
            for (int r = 0; r < 4; ++r) fbuf[(erow0 + r) * 20 + j] = hnv[r];
        } else {
            #pragma unroll
            for (int r = 0; r < 4; ++r)
                __builtin_nontemporal_store(hnv[r], &out[(size_t)t * BH + (erow0 + r) * HID + ecol]);
        }
        if (t == SEQ - 1) {
            #pragma unroll
            for (int r = 0; r < 4; ++r) {
                __builtin_nontemporal_store(hnv[r], &out[OUT_H + pool * BH + (erow0 + r) * HID + ecol]);
                __builtin_nontemporal_store(cnv[r], &out[OUT_C + pool * BH + (erow0 + r) * HID + ecol]);
            }
        }
        __syncthreads();
        if (tid < 128) {
            const int row = tid >> 1, c8 = (tid & 1) * 8;
            f16x8 v = *(const f16x8*)&hbuf[row * 24 + c8];
            GST16(ho + w * 1024 + row * 16 + c8, v);
        }
        if (pool == 0) {
            const int row = tid >> 2, c4 = (tid & 3) * 4;
            f32x4 v = *(const f32x4*)&fbuf[row * 20 + c4];
            GST16(ring + (t & 3) * BH + w * 1024 + row * 16 + c4, v);
        }
        VMWAIT();
        __syncthreads();
        if (tid == 0) FLAGST(flg + (size_t)(pool * 6 + 5) * 512 + w * 16, 6u * t + 6u);
    }
}

// ---------------- host launch ----------------
extern "C" void kernel_launch(void* const* d_in, const int* in_sizes, int n_in,
                              void* d_out, int out_size, void* d_ws, size_t ws_size,
                              hipStream_t stream) {
    const float* in_seq  = (const float*)d_in[0];
    const float* l1_mogW = (const float*)d_in[1];
    const float* l1_mogb = (const float*)d_in[2];
    const float* l1_Wih  = (const float*)d_in[3];
    const float* l1_Whh  = (const float*)d_in[4];
    const float* l1_bih  = (const float*)d_in[5];
    const float* l1_bhh  = (const float*)d_in[6];
    const float* l2_mogW = (const float*)d_in[7];
    const float* l2_mogb = (const float*)d_in[8];
    const float* l2_Wih  = (const float*)d_in[9];
    const float* l2_Whh  = (const float*)d_in[10];
    const float* l2_bih  = (const float*)d_in[11];
    const float* l2_bhh  = (const float*)d_in[12];

    hipMemsetAsync(d_ws, 0, ZERO_PREFIX, stream);

    prologue_convert<<<256, 256, 0, stream>>>(l1_mogW, l1_Wih, l1_Whh,
                                              l2_mogW, l2_Wih, l2_Whh, (char*)d_ws);

    moglstm_persist<<<64, NTHR, 90112, stream>>>(in_seq, l1_mogb, l2_mogb,
                                                 l1_bih, l1_bhh, l2_bih, l2_bhh,
                                                 (float*)d_out, (char*)d_ws);
}